// Round 2
// baseline (6616.990 us; speedup 1.0000x reference)
//
#include <hip/hip_runtime.h>
#include <cstdint>
#include <cmath>

// B=8, x reshaped (8,15,512,512) fp32.
// gating: conv7x7 s2 p3 (15->64, 256x256) -> BN -> relu -> maxpool3x3 s2 p1 -> mean -> FC(64->3) -> top-1
// expert (selected, top-1 => gate weight 1.0): conv7x7 s2 p3 (15->64) relu -> conv3x3 s2 p1 (64->128) relu
//         -> conv3x3 s1 p1 (128->128)+b relu -> conv1x1 (128->5)+b
// out: hm(8,1,128,128) | wh(8,2,128,128) | reg(8,2,128,128) | 0.01*aux = 655361 floats
//
// R2 design: NO LDS, NO barriers in conv kernels. Activations via per-thread
// global loads (vmcnt), weights via wave-uniform s_load (lgkmcnt) -> the two
// counters pipeline independently (R1 mixed ds_read+s_load in lgkmcnt => 70% stall).

// ---------------- conv 7x7 stride2 pad3, Cin=15, Cout=64, 512->256 ----------------
// MODE 0: gating weights + BN + relu. MODE 1: per-batch expert weights + relu.
template<int MODE>
__global__ __launch_bounds__(256) void conv7_k(
    const float* __restrict__ in, const float* __restrict__ w,
    const float* __restrict__ bn_g, const float* __restrict__ bn_b,
    const float* __restrict__ bn_m, const float* __restrict__ bn_v,
    const int* __restrict__ sel, float* __restrict__ out)
{
  const int bid = blockIdx.x;
  const int xt = bid & 7;          // 8 x-tiles of 32
  const int yt = (bid >> 3) & 31;  // 32 y-tiles of 8
  const int cb = (bid >> 8) & 1;   // 2 cout halves of 32
  const int b  = bid >> 9;         // 8 batches
  const int tid = threadIdx.x;
  const int tx = tid & 31, ty = tid >> 5;
  const int ox = xt * 32 + tx, oy = yt * 8 + ty;
  const int ix0 = 2 * ox - 3, iy0 = 2 * oy - 3;  // per-thread window origin

  // block-uniform interior test (all 49 taps in-bounds for every thread)
  const bool interior = (xt >= 1) && (xt <= 6) && (yt >= 1) && (yt <= 30);

  const float* wbase;
  if constexpr (MODE == 0) {
    wbase = w + (size_t)(cb * 32) * (15 * 49);
  } else {
    const int e = sel[b];
    wbase = w + ((size_t)e * 64 + cb * 32) * (15 * 49);
  }
  const float* inb = in + (size_t)b * (15 * 512 * 512);

  float acc[32];
#pragma unroll
  for (int i = 0; i < 32; ++i) acc[i] = 0.f;

#pragma unroll 1
  for (int cin = 0; cin < 15; ++cin) {
    const float* ip = inb + (size_t)cin * (512 * 512);
    float v[49];
    if (interior) {
      const float* ipt = ip + iy0 * 512 + ix0;
#pragma unroll
      for (int ky = 0; ky < 7; ++ky)
#pragma unroll
        for (int kx = 0; kx < 7; ++kx)
          v[ky * 7 + kx] = ipt[ky * 512 + kx];
    } else {
#pragma unroll
      for (int ky = 0; ky < 7; ++ky) {
        const int gy = iy0 + ky;
        const bool oky = (unsigned)gy < 512u;
        const int cy = oky ? gy : 0;
#pragma unroll
        for (int kx = 0; kx < 7; ++kx) {
          const int gx = ix0 + kx;
          const bool ok = oky && ((unsigned)gx < 512u);
          const int cx = ((unsigned)gx < 512u) ? gx : 0;
          const float val = ip[cy * 512 + cx];
          v[ky * 7 + kx] = ok ? val : 0.f;
        }
      }
    }
    const float* wcin = wbase + cin * 49;
#pragma unroll
    for (int co = 0; co < 32; ++co) {
      const float* wc = wcin + (size_t)co * (15 * 49);
#pragma unroll
      for (int k = 0; k < 49; ++k) acc[co] = fmaf(wc[k], v[k], acc[co]);
    }
  }

  const size_t obase = (((size_t)b * 64 + cb * 32) * 65536) + (size_t)(oy * 256 + ox);
#pragma unroll
  for (int co = 0; co < 32; ++co) {
    float r = acc[co];
    if constexpr (MODE == 0) {
      const int c = cb * 32 + co;
      const float sc = bn_g[c] * rsqrtf(bn_v[c] + 1e-5f);
      r = r * sc + (bn_b[c] - bn_m[c] * sc);
    }
    r = fmaxf(r, 0.f);
    out[obase + (size_t)co * 65536] = r;
  }
}

// ---------------- maxpool 3x3 s2 p1 (256->128) + spatial mean ----------------
__global__ __launch_bounds__(256) void pool_mean_k(
    const float* __restrict__ f, float* __restrict__ pooled)
{
  const int bc = blockIdx.x;  // b*64 + c, 512 blocks
  const float* src = f + (size_t)bc * 65536;
  float sum = 0.f;
  for (int i = threadIdx.x; i < 16384; i += 256) {
    const int ph = i >> 7, pw = i & 127;
    const int y0 = 2 * ph - 1, x0 = 2 * pw - 1;
    float m = -1e30f;
#pragma unroll
    for (int dy = 0; dy < 3; ++dy) {
      const int y = y0 + dy;
      if ((unsigned)y < 256u) {
#pragma unroll
        for (int dx = 0; dx < 3; ++dx) {
          const int x = x0 + dx;
          if ((unsigned)x < 256u) m = fmaxf(m, src[y * 256 + x]);
        }
      }
    }
    sum += m;
  }
  __shared__ float red[4];
#pragma unroll
  for (int off = 32; off > 0; off >>= 1) sum += __shfl_down(sum, off, 64);
  if ((threadIdx.x & 63) == 0) red[threadIdx.x >> 6] = sum;
  __syncthreads();
  if (threadIdx.x == 0)
    pooled[bc] = (red[0] + red[1] + red[2] + red[3]) * (1.f / 16384.f);
}

// ---------------- FC + top-1 + aux loss ----------------
__global__ __launch_bounds__(64) void gate_k(
    const float* __restrict__ pooled, const float* __restrict__ fcw,
    const float* __restrict__ fcb, int* __restrict__ sel, float* __restrict__ out_aux)
{
  __shared__ float probs[8][3];
  __shared__ int sidx[8];
  const int b = threadIdx.x;
  if (b < 8) {
    float l[3];
#pragma unroll
    for (int e = 0; e < 3; ++e) {
      float s = fcb[e];
      for (int c = 0; c < 64; ++c) s = fmaf(pooled[b * 64 + c], fcw[e * 64 + c], s);
      l[e] = s;
    }
    int best = 0;
    if (l[1] > l[best]) best = 1;
    if (l[2] > l[best]) best = 2;
    sel[b] = best;
    sidx[b] = best;
    const float m = fmaxf(l[0], fmaxf(l[1], l[2]));
    const float e0 = expf(l[0] - m), e1 = expf(l[1] - m), e2 = expf(l[2] - m);
    const float inv = 1.f / (e0 + e1 + e2);
    probs[b][0] = e0 * inv; probs[b][1] = e1 * inv; probs[b][2] = e2 * inv;
  }
  __syncthreads();
  if (threadIdx.x == 0) {
    float cnt[3] = {0.f, 0.f, 0.f}, pr[3] = {0.f, 0.f, 0.f};
    for (int bb = 0; bb < 8; ++bb) {
      cnt[sidx[bb]] += 1.f;
#pragma unroll
      for (int e = 0; e < 3; ++e) pr[e] += probs[bb][e];
    }
    float aux = 0.f;
#pragma unroll
    for (int e = 0; e < 3; ++e) aux += (cnt[e] * 0.125f) * (pr[e] * 0.125f);
    *out_aux = 0.01f * (3.f * aux);
  }
}

// ---------------- conv 3x3, Cout=128, per-batch expert weights, relu ----------------
// STRIDE=2: 256->128, CINC=64 (conv2).  STRIDE=1: 128->128, CINC=128, +bias (head1).
template<int STRIDE, int CINC, int INSZ, int OUTSZ, bool HASBIAS>
__global__ __launch_bounds__(256) void conv3_k(
    const float* __restrict__ in, const float* __restrict__ w,
    const float* __restrict__ bias, const int* __restrict__ sel,
    float* __restrict__ out)
{
  const int bid = blockIdx.x;
  const int xt = bid & 3;          // 4 x-tiles of 32
  const int yt = (bid >> 2) & 15;  // 16 y-tiles of 8
  const int cb = (bid >> 6) & 1;   // 2 cout halves of 64
  const int b  = bid >> 7;         // 8 batches
  const int tid = threadIdx.x;
  const int tx = tid & 31, ty = tid >> 5;
  const int ox = xt * 32 + tx, oy = yt * 8 + ty;
  const int ix0 = STRIDE * ox - 1, iy0 = STRIDE * oy - 1;

  // block-uniform interior test
  const int xlo = STRIDE * (xt * 32) - 1, xhi = STRIDE * (xt * 32 + 31) + 1;
  const int ylo = STRIDE * (yt * 8) - 1,  yhi = STRIDE * (yt * 8 + 7) + 1;
  const bool interior = (xlo >= 0) && (xhi < INSZ) && (ylo >= 0) && (yhi < INSZ);

  const int e = sel[b];
  const float* wbase = w + ((size_t)e * 128 + cb * 64) * (CINC * 9);
  const float* inb = in + (size_t)b * CINC * (INSZ * INSZ);

  float acc[64];
#pragma unroll
  for (int i = 0; i < 64; ++i) acc[i] = 0.f;

#pragma unroll 1
  for (int cin = 0; cin < CINC; ++cin) {
    const float* ip = inb + (size_t)cin * (INSZ * INSZ);
    float v[9];
    if (interior) {
      const float* ipt = ip + iy0 * INSZ + ix0;
#pragma unroll
      for (int ky = 0; ky < 3; ++ky)
#pragma unroll
        for (int kx = 0; kx < 3; ++kx)
          v[ky * 3 + kx] = ipt[ky * INSZ + kx];
    } else {
#pragma unroll
      for (int ky = 0; ky < 3; ++ky) {
        const int gy = iy0 + ky;
        const bool oky = (unsigned)gy < (unsigned)INSZ;
        const int cy = oky ? gy : 0;
#pragma unroll
        for (int kx = 0; kx < 3; ++kx) {
          const int gx = ix0 + kx;
          const bool ok = oky && ((unsigned)gx < (unsigned)INSZ);
          const int cx = ((unsigned)gx < (unsigned)INSZ) ? gx : 0;
          const float val = ip[cy * INSZ + cx];
          v[ky * 3 + kx] = ok ? val : 0.f;
        }
      }
    }
    const float* wcin = wbase + cin * 9;
#pragma unroll
    for (int co = 0; co < 64; ++co) {
      const float* wc = wcin + (size_t)co * (CINC * 9);
#pragma unroll
      for (int k = 0; k < 9; ++k) acc[co] = fmaf(wc[k], v[k], acc[co]);
    }
  }

  const size_t obase = (((size_t)b * 128 + cb * 64) * (OUTSZ * OUTSZ))
                     + (size_t)(oy * OUTSZ + ox);
#pragma unroll
  for (int co = 0; co < 64; ++co) {
    float r = acc[co];
    if constexpr (HASBIAS) r += bias[e * 128 + cb * 64 + co];
    r = fmaxf(r, 0.f);
    out[obase + (size_t)co * (OUTSZ * OUTSZ)] = r;
  }
}

// ---------------- head 1x1 conv 128->5 + bias, scatter to hm/wh/reg ----------------
__global__ __launch_bounds__(256) void head2_k(
    const float* __restrict__ in, const float* __restrict__ w,
    const float* __restrict__ b2, const int* __restrict__ sel,
    float* __restrict__ out)
{
  const int bid = blockIdx.x;          // 512 = 8 b * 64 pixel-blocks
  const int b = bid >> 6;
  const int p = ((bid & 63) << 8) + threadIdx.x;  // 0..16383
  const int e = sel[b];
  const float* wp = w + (size_t)e * 5 * 128;      // (5,128)
  const float* ip = in + (((size_t)b * 128) << 14) + p;
  float a0 = 0.f, a1 = 0.f, a2 = 0.f, a3 = 0.f, a4 = 0.f;
#pragma unroll 4
  for (int c = 0; c < 128; ++c) {
    const float v = ip[(size_t)c << 14];
    a0 = fmaf(v, wp[c], a0);
    a1 = fmaf(v, wp[128 + c], a1);
    a2 = fmaf(v, wp[256 + c], a2);
    a3 = fmaf(v, wp[384 + c], a3);
    a4 = fmaf(v, wp[512 + c], a4);
  }
  a0 += b2[e * 5 + 0]; a1 += b2[e * 5 + 1]; a2 += b2[e * 5 + 2];
  a3 += b2[e * 5 + 3]; a4 += b2[e * 5 + 4];
  out[(b << 14) + p] = a0;                         // hm
  out[131072 + ((b * 2 + 0) << 14) + p] = a1;      // wh c0
  out[131072 + ((b * 2 + 1) << 14) + p] = a2;      // wh c1
  out[393216 + ((b * 2 + 0) << 14) + p] = a3;      // reg c0
  out[393216 + ((b * 2 + 1) << 14) + p] = a4;      // reg c1
}

extern "C" void kernel_launch(void* const* d_in, const int* in_sizes, int n_in,
                              void* d_out, int out_size, void* d_ws, size_t ws_size,
                              hipStream_t stream) {
  const float* x          = (const float*)d_in[0];
  const float* g_conv_w   = (const float*)d_in[1];
  const float* g_bn_gamma = (const float*)d_in[2];
  const float* g_bn_beta  = (const float*)d_in[3];
  const float* g_bn_mean  = (const float*)d_in[4];
  const float* g_bn_var   = (const float*)d_in[5];
  const float* g_fc_w     = (const float*)d_in[6];
  const float* g_fc_b     = (const float*)d_in[7];
  const float* e_conv1_w  = (const float*)d_in[8];
  const float* e_conv2_w  = (const float*)d_in[9];
  const float* e_head_w1  = (const float*)d_in[10];
  const float* e_head_b1  = (const float*)d_in[11];
  const float* e_head_w2  = (const float*)d_in[12];
  const float* e_head_b2  = (const float*)d_in[13];
  float* out = (float*)d_out;

  // workspace layout (needs ~201.3 MB)
  float* buf1   = (float*)d_ws;          // 8*64*256*256  = 33,554,432 f (reused for head1 out)
  float* buf2   = buf1 + 33554432;       // 8*128*128*128 = 16,777,216 f
  float* pooled = buf2 + 16777216;       // 512 f
  int*   sel    = (int*)(pooled + 512);  // 8 ints

  // gating path
  conv7_k<0><<<4096, 256, 0, stream>>>(x, g_conv_w, g_bn_gamma, g_bn_beta,
                                       g_bn_mean, g_bn_var, nullptr, buf1);
  pool_mean_k<<<512, 256, 0, stream>>>(buf1, pooled);
  gate_k<<<1, 64, 0, stream>>>(pooled, g_fc_w, g_fc_b, sel, out + 655360);

  // selected-expert path (top-1 => weight 1.0, single expert per batch item)
  conv7_k<1><<<4096, 256, 0, stream>>>(x, e_conv1_w, nullptr, nullptr,
                                       nullptr, nullptr, sel, buf1);
  conv3_k<2, 64, 256, 128, false><<<1024, 256, 0, stream>>>(buf1, e_conv2_w, nullptr, sel, buf2);
  conv3_k<1, 128, 128, 128, true><<<1024, 256, 0, stream>>>(buf2, e_head_w1, e_head_b1, sel, buf1);
  head2_k<<<512, 256, 0, stream>>>(buf1, e_head_w2, e_head_b2, sel, out);
}

// Round 3
// 2481.088 us; speedup vs baseline: 2.6670x; 2.6670x over previous
//
#include <hip/hip_runtime.h>
#include <cstdint>
#include <cmath>

// B=8, x reshaped (8,15,512,512) fp32.
// gating: conv7x7 s2 p3 (15->64, 256x256) -> BN -> relu -> maxpool3x3 s2 p1 -> mean -> FC(64->3) -> top-1
// expert (selected, top-1 => gate weight 1.0): conv7x7 s2 p3 (15->64) relu -> conv3x3 s2 p1 (64->128) relu
//         -> conv3x3 s1 p1 (128->128)+b relu -> conv1x1 (128->5)+b
// out: hm | wh | reg | 0.01*aux = 655361 floats
//
// R3: implicit-GEMM conv via v_mfma_f32_16x16x32_f16.
//   A (weights, M=cout x K) read directly from global as row fragments.
//   B (im2col, K x N=128 pixels) staged per 32-K chunk in LDS [n][k], 80B row
//   stride (8-phase bank-disjoint for ds_read_b128 frag reads).

typedef _Float16 f16x8 __attribute__((ext_vector_type(8)));
typedef _Float16 f16x4 __attribute__((ext_vector_type(4)));
typedef float f32x4 __attribute__((ext_vector_type(4)));

// MODE 0: gating (BN+relu, weights not expert-indexed)
// MODE 1: relu, expert-indexed
// MODE 2: +bias (in p_bias) relu, expert-indexed
template<int COUT, int CIN, int KSZ, int S, int P, int INSZ, int OUTSZ, int MODE>
__global__ __launch_bounds__(256) void convmfma_k(
    const float* __restrict__ in, const float* __restrict__ w,
    const float* __restrict__ bn_g, const float* __restrict__ bn_b,
    const float* __restrict__ bn_m, const float* __restrict__ bn_v,
    const float* __restrict__ p_bias,
    const int* __restrict__ sel, float* __restrict__ out)
{
  constexpr int K   = CIN * KSZ * KSZ;
  constexpr int KC  = (K + 31) / 32;       // k-chunks of 32
  constexpr int KHW = KSZ * KSZ;
  constexpr int TPR = OUTSZ / 128;         // pixel tiles per output row
  constexpr int MF  = 4;                   // 16-wide m-frags per wave
  constexpr int NF  = (COUT == 128) ? 4 : 2;
  constexpr bool AALIGN = (K % 8 == 0);    // W rows 32B-aligned -> float4 loads

  __shared__ _Float16 ldsB[128 * 40];      // [n][32 k + 8 pad], 80B rows

  const int bid = blockIdx.x;
  const int xt  = bid % TPR;
  const int oy  = (bid / TPR) % OUTSZ;
  const int b   = bid / (TPR * OUTSZ);
  const int nx0 = xt * 128;

  const int tid  = threadIdx.x;
  const int wv   = tid >> 6;
  const int lane = tid & 63;
  const int ln15 = lane & 15, quad = lane >> 4;

  const int mwb = (COUT == 128) ? (wv >> 1) * 64 : 0;
  const int nwb = (COUT == 128) ? (wv & 1) * 64 : wv * 32;

  int e = 0;
  if constexpr (MODE != 0) e = sel[b];
  const float* wbase = w + (size_t)e * COUT * K;
  const float* inb   = in + (size_t)b * CIN * (INSZ * INSZ);

  // B staging: thread covers k = s_kq*4+0..3, n = s_nc + {0,32,64,96}
  const int s_kq = tid >> 5;
  const int s_nc = tid & 31;

  f32x4 acc[MF][NF];
#pragma unroll
  for (int f = 0; f < MF; ++f)
#pragma unroll
    for (int g = 0; g < NF; ++g) acc[f][g] = (f32x4){0.f, 0.f, 0.f, 0.f};

#pragma unroll 1
  for (int kc = 0; kc < KC; ++kc) {
    const int k0 = kc * 32;
    __syncthreads();
    // ---- stage B: gather 4x4 sub-tile, cvt fp16, write [n][k] ----
    float vals[4][4];
#pragma unroll
    for (int ki = 0; ki < 4; ++ki) {
      const int kk = k0 + s_kq * 4 + ki;
      const int cin = kk / KHW;
      const int rem = kk - cin * KHW;
      const int ky = rem / KSZ;
      const int kx = rem - ky * KSZ;
      const int iy = S * oy + ky - P;
      const bool okr = (kk < K) && ((unsigned)iy < (unsigned)INSZ);
      const int rofs = cin * (INSZ * INSZ) + iy * INSZ;
#pragma unroll
      for (int nj = 0; nj < 4; ++nj) {
        const int ix = S * (nx0 + s_nc + 32 * nj) + kx - P;
        float v = 0.f;
        if (okr && (unsigned)ix < (unsigned)INSZ) v = inb[rofs + ix];
        vals[ki][nj] = v;
      }
    }
#pragma unroll
    for (int nj = 0; nj < 4; ++nj) {
      f16x4 h;
      h[0] = (_Float16)vals[0][nj]; h[1] = (_Float16)vals[1][nj];
      h[2] = (_Float16)vals[2][nj]; h[3] = (_Float16)vals[3][nj];
      *(f16x4*)&ldsB[(s_nc + 32 * nj) * 40 + s_kq * 4] = h;
    }
    __syncthreads();

    // ---- A frags from global (rows of W are contiguous K) ----
    f16x8 af[MF];
#pragma unroll
    for (int f = 0; f < MF; ++f) {
      const float* ap = wbase + (size_t)(mwb + f * 16 + ln15) * K + k0 + quad * 8;
      float av[8];
      if constexpr (AALIGN) {
        const float4 a0 = *(const float4*)ap;
        const float4 a1 = *(const float4*)(ap + 4);
        av[0] = a0.x; av[1] = a0.y; av[2] = a0.z; av[3] = a0.w;
        av[4] = a1.x; av[5] = a1.y; av[6] = a1.z; av[7] = a1.w;
      } else {
        if (k0 + 32 <= K) {
#pragma unroll
          for (int j = 0; j < 8; ++j) av[j] = ap[j];
        } else {
#pragma unroll
          for (int j = 0; j < 8; ++j) {
            const int kk = k0 + quad * 8 + j;
            av[j] = (kk < K) ? ap[j] : 0.f;
          }
        }
      }
#pragma unroll
      for (int j = 0; j < 8; ++j) af[f][j] = (_Float16)av[j];
    }

    // ---- B frags from LDS ----
    f16x8 bf[NF];
#pragma unroll
    for (int g = 0; g < NF; ++g)
      bf[g] = *(const f16x8*)&ldsB[(nwb + g * 16 + ln15) * 40 + quad * 8];

    // ---- MFMA ----
#pragma unroll
    for (int f = 0; f < MF; ++f)
#pragma unroll
      for (int g = 0; g < NF; ++g)
        acc[f][g] = __builtin_amdgcn_mfma_f32_16x16x32_f16(af[f], bf[g], acc[f][g], 0, 0, 0);
  }

  // ---- epilogue: C[row=quad*4+r][col=ln15] ----
#pragma unroll
  for (int f = 0; f < MF; ++f) {
#pragma unroll
    for (int r = 0; r < 4; ++r) {
      const int cout = mwb + f * 16 + quad * 4 + r;
      float scl = 1.f, add = 0.f;
      if constexpr (MODE == 0) {
        const float sc = bn_g[cout] * rsqrtf(bn_v[cout] + 1e-5f);
        scl = sc; add = bn_b[cout] - bn_m[cout] * sc;
      } else if constexpr (MODE == 2) {
        add = p_bias[e * COUT + cout];
      }
      const size_t obase = ((size_t)(b * COUT + cout) * OUTSZ + oy) * OUTSZ + nx0;
#pragma unroll
      for (int g = 0; g < NF; ++g) {
        float v = acc[f][g][r] * scl + add;
        v = fmaxf(v, 0.f);
        out[obase + nwb + g * 16 + ln15] = v;
      }
    }
  }
}

// ---------------- maxpool 3x3 s2 p1 (256->128) + spatial mean ----------------
__global__ __launch_bounds__(256) void pool_mean_k(
    const float* __restrict__ f, float* __restrict__ pooled)
{
  const int bc = blockIdx.x;  // b*64 + c, 512 blocks
  const float* src = f + (size_t)bc * 65536;
  float sum = 0.f;
  for (int i = threadIdx.x; i < 16384; i += 256) {
    const int ph = i >> 7, pw = i & 127;
    const int y0 = 2 * ph - 1, x0 = 2 * pw - 1;
    float m = -1e30f;
#pragma unroll
    for (int dy = 0; dy < 3; ++dy) {
      const int y = y0 + dy;
      if ((unsigned)y < 256u) {
#pragma unroll
        for (int dx = 0; dx < 3; ++dx) {
          const int x = x0 + dx;
          if ((unsigned)x < 256u) m = fmaxf(m, src[y * 256 + x]);
        }
      }
    }
    sum += m;
  }
  __shared__ float red[4];
#pragma unroll
  for (int off = 32; off > 0; off >>= 1) sum += __shfl_down(sum, off, 64);
  if ((threadIdx.x & 63) == 0) red[threadIdx.x >> 6] = sum;
  __syncthreads();
  if (threadIdx.x == 0)
    pooled[bc] = (red[0] + red[1] + red[2] + red[3]) * (1.f / 16384.f);
}

// ---------------- FC + top-1 + aux loss ----------------
__global__ __launch_bounds__(64) void gate_k(
    const float* __restrict__ pooled, const float* __restrict__ fcw,
    const float* __restrict__ fcb, int* __restrict__ sel, float* __restrict__ out_aux)
{
  __shared__ float probs[8][3];
  __shared__ int sidx[8];
  const int b = threadIdx.x;
  if (b < 8) {
    float l[3];
#pragma unroll
    for (int e = 0; e < 3; ++e) {
      float s = fcb[e];
      for (int c = 0; c < 64; ++c) s = fmaf(pooled[b * 64 + c], fcw[e * 64 + c], s);
      l[e] = s;
    }
    int best = 0;
    if (l[1] > l[best]) best = 1;
    if (l[2] > l[best]) best = 2;
    sel[b] = best;
    sidx[b] = best;
    const float m = fmaxf(l[0], fmaxf(l[1], l[2]));
    const float e0 = expf(l[0] - m), e1 = expf(l[1] - m), e2 = expf(l[2] - m);
    const float inv = 1.f / (e0 + e1 + e2);
    probs[b][0] = e0 * inv; probs[b][1] = e1 * inv; probs[b][2] = e2 * inv;
  }
  __syncthreads();
  if (threadIdx.x == 0) {
    float cnt[3] = {0.f, 0.f, 0.f}, pr[3] = {0.f, 0.f, 0.f};
    for (int bb = 0; bb < 8; ++bb) {
      cnt[sidx[bb]] += 1.f;
#pragma unroll
      for (int e = 0; e < 3; ++e) pr[e] += probs[bb][e];
    }
    float aux = 0.f;
#pragma unroll
    for (int e = 0; e < 3; ++e) aux += (cnt[e] * 0.125f) * (pr[e] * 0.125f);
    *out_aux = 0.01f * (3.f * aux);
  }
}

// ---------------- head 1x1 conv 128->5 + bias, scatter to hm/wh/reg ----------------
__global__ __launch_bounds__(256) void head2_k(
    const float* __restrict__ in, const float* __restrict__ w,
    const float* __restrict__ b2, const int* __restrict__ sel,
    float* __restrict__ out)
{
  const int bid = blockIdx.x;          // 512 = 8 b * 64 pixel-blocks
  const int b = bid >> 6;
  const int p = ((bid & 63) << 8) + threadIdx.x;  // 0..16383
  const int e = sel[b];
  const float* wp = w + (size_t)e * 5 * 128;      // (5,128)
  const float* ip = in + (((size_t)b * 128) << 14) + p;
  float a0 = 0.f, a1 = 0.f, a2 = 0.f, a3 = 0.f, a4 = 0.f;
#pragma unroll 4
  for (int c = 0; c < 128; ++c) {
    const float v = ip[(size_t)c << 14];
    a0 = fmaf(v, wp[c], a0);
    a1 = fmaf(v, wp[128 + c], a1);
    a2 = fmaf(v, wp[256 + c], a2);
    a3 = fmaf(v, wp[384 + c], a3);
    a4 = fmaf(v, wp[512 + c], a4);
  }
  a0 += b2[e * 5 + 0]; a1 += b2[e * 5 + 1]; a2 += b2[e * 5 + 2];
  a3 += b2[e * 5 + 3]; a4 += b2[e * 5 + 4];
  out[(b << 14) + p] = a0;                         // hm
  out[131072 + ((b * 2 + 0) << 14) + p] = a1;      // wh c0
  out[131072 + ((b * 2 + 1) << 14) + p] = a2;      // wh c1
  out[393216 + ((b * 2 + 0) << 14) + p] = a3;      // reg c0
  out[393216 + ((b * 2 + 1) << 14) + p] = a4;      // reg c1
}

extern "C" void kernel_launch(void* const* d_in, const int* in_sizes, int n_in,
                              void* d_out, int out_size, void* d_ws, size_t ws_size,
                              hipStream_t stream) {
  const float* x          = (const float*)d_in[0];
  const float* g_conv_w   = (const float*)d_in[1];
  const float* g_bn_gamma = (const float*)d_in[2];
  const float* g_bn_beta  = (const float*)d_in[3];
  const float* g_bn_mean  = (const float*)d_in[4];
  const float* g_bn_var   = (const float*)d_in[5];
  const float* g_fc_w     = (const float*)d_in[6];
  const float* g_fc_b     = (const float*)d_in[7];
  const float* e_conv1_w  = (const float*)d_in[8];
  const float* e_conv2_w  = (const float*)d_in[9];
  const float* e_head_w1  = (const float*)d_in[10];
  const float* e_head_b1  = (const float*)d_in[11];
  const float* e_head_w2  = (const float*)d_in[12];
  const float* e_head_b2  = (const float*)d_in[13];
  float* out = (float*)d_out;

  // workspace layout (~201.3 MB)
  float* buf1   = (float*)d_ws;          // 8*64*256*256  = 33,554,432 f (reused for head1 out)
  float* buf2   = buf1 + 33554432;       // 8*128*128*128 = 16,777,216 f
  float* pooled = buf2 + 16777216;       // 512 f
  int*   sel    = (int*)(pooled + 512);  // 8 ints

  // gating path
  convmfma_k<64, 15, 7, 2, 3, 512, 256, 0><<<4096, 256, 0, stream>>>(
      x, g_conv_w, g_bn_gamma, g_bn_beta, g_bn_mean, g_bn_var, nullptr, nullptr, buf1);
  pool_mean_k<<<512, 256, 0, stream>>>(buf1, pooled);
  gate_k<<<1, 64, 0, stream>>>(pooled, g_fc_w, g_fc_b, sel, out + 655360);

  // selected-expert path (top-1 => gate weight 1.0)
  convmfma_k<64, 15, 7, 2, 3, 512, 256, 1><<<4096, 256, 0, stream>>>(
      x, e_conv1_w, nullptr, nullptr, nullptr, nullptr, nullptr, sel, buf1);
  convmfma_k<128, 64, 3, 2, 1, 256, 128, 1><<<1024, 256, 0, stream>>>(
      buf1, e_conv2_w, nullptr, nullptr, nullptr, nullptr, nullptr, sel, buf2);
  convmfma_k<128, 128, 3, 1, 1, 128, 128, 2><<<1024, 256, 0, stream>>>(
      buf2, e_head_w1, nullptr, nullptr, nullptr, nullptr, e_head_b1, sel, buf1);
  head2_k<<<512, 256, 0, stream>>>(buf1, e_head_w2, e_head_b2, sel, out);
}

// Round 4
// 982.789 us; speedup vs baseline: 6.7329x; 2.5245x over previous
//
#include <hip/hip_runtime.h>
#include <cstdint>
#include <cmath>

// B=8, x reshaped (8,15,512,512) fp32.
// gating: conv7x7 s2 p3 (15->64, 256x256) -> BN -> relu -> maxpool3x3 s2 p1 -> mean -> FC(64->3) -> top-1
// expert (selected, top-1 => gate weight 1.0): conv7x7 s2 p3 (15->64) relu -> conv3x3 s2 p1 (64->128) relu
//         -> conv3x3 s1 p1 (128->128)+b relu -> conv1x1 (128->5)+b
// out: hm | wh | reg | 0.01*aux = 655361 floats
//
// R4: direct-conv MFMA, no LDS/no barriers in convs.
//  - x pre-converted to fp16 channel-last [b][512][512][16] (cin 15 padded to 16).
//  - conv7 K-chunks = (2 kx taps)x(16 cin); kx padded 7->8 (4 pairs/ky). B-frag is one
//    global dwordx4: quads cover (tap,cin-half) -> 64B fully consumed, lanes coalesce.
//  - conv3s K-chunks = 32 cin from channel-last activations.
//  - weights pre-packed to MFMA A-fragment order [..][cout][32] fp16.
//  - All activations fp16 channel-last; epilogues fuse BN/bias+relu.
// Fragment mappings (validated in R3, absmax 7.8e-3):
//   A[m=lane&15][k=quad*8+j], B[k=quad*8+j][n=lane&15], C[row=quad*4+r][col=lane&15].

typedef _Float16 f16x8 __attribute__((ext_vector_type(8)));
typedef _Float16 f16x4 __attribute__((ext_vector_type(4)));
typedef float f32x4 __attribute__((ext_vector_type(4)));

// ---------------- prep: x fp32 [b][15][512][512] -> fp16 [b][512][512][16] ----------------
__global__ __launch_bounds__(256) void prep_x_k(
    const float* __restrict__ x, _Float16* __restrict__ xp)
{
  const int t = blockIdx.x * 256 + threadIdx.x;   // 0 .. 8*262144-1
  const int pix = t & 262143;
  const int b   = t >> 18;
  const float* src = x + (size_t)b * 15 * 262144 + pix;
  f16x8 lo, hi;
#pragma unroll
  for (int c = 0; c < 8; ++c)  lo[c] = (_Float16)src[(size_t)c * 262144];
#pragma unroll
  for (int c = 8; c < 15; ++c) hi[c - 8] = (_Float16)src[(size_t)c * 262144];
  hi[7] = (_Float16)0.f;
  *(f16x8*)&xp[(size_t)t * 16]     = lo;
  *(f16x8*)&xp[(size_t)t * 16 + 8] = hi;
}

// ---------------- prep: conv7 weights -> [set4][ky7][pair4][cout64][32] fp16 ----------------
// set0 = gating, set1..3 = experts. k within 32 = t*16+cin, kx = 2*pair+t.
__global__ __launch_bounds__(256) void prep_w7_k(
    const float* __restrict__ gw, const float* __restrict__ ew,
    _Float16* __restrict__ wp)
{
  const int i = blockIdx.x * 256 + threadIdx.x;   // 0 .. 229375
  const int kk   = i & 31;
  const int cout = (i >> 5) & 63;
  const int pair = (i >> 11) & 3;
  const int v    = i >> 13;
  const int ky = v % 7, set = v / 7;
  const int t = kk >> 4, cin = kk & 15;
  const int kx = 2 * pair + t;
  float val = 0.f;
  if (cin < 15 && kx < 7) {
    if (set == 0) val = gw[((cout * 15 + cin) * 7 + ky) * 7 + kx];
    else          val = ew[((((set - 1) * 64 + cout) * 15 + cin) * 7 + ky) * 7 + kx];
  }
  wp[i] = (_Float16)val;
}

// ---------------- prep: 3x3 weights [3][128][CINC][3][3] -> [e][tap9][ch][cout128][32] ----
template<int CINC>
__global__ __launch_bounds__(256) void prep_w3_k(
    const float* __restrict__ w, _Float16* __restrict__ wp)
{
  constexpr int CH = CINC / 32;
  const int i = blockIdx.x * 256 + threadIdx.x;   // 0 .. 3*9*CH*128*32-1
  const int kk   = i & 31;
  const int cout = (i >> 5) & 127;
  int rest = i >> 12;
  const int ch  = rest % CH;  rest /= CH;
  const int tap = rest % 9;
  const int e   = rest / 9;
  const int cin = ch * 32 + kk;
  wp[i] = (_Float16)w[((size_t)(e * 128 + cout) * CINC + cin) * 9 + tap];
}

// ---------------- conv7x7 s2 p3 (16ch-last in, 64ch-last fp16 out) ----------------
// MODE 0: gating set=0, BN+relu. MODE 1: expert set=1+sel[b], relu.
template<int MODE>
__global__ __launch_bounds__(256) void conv7m_k(
    const _Float16* __restrict__ xp, const _Float16* __restrict__ wp,
    const float* __restrict__ bn_g, const float* __restrict__ bn_b,
    const float* __restrict__ bn_m, const float* __restrict__ bn_v,
    const int* __restrict__ sel, _Float16* __restrict__ out)
{
  const int oy = blockIdx.x & 255, b = blockIdx.x >> 8;
  const int wv = threadIdx.x >> 6, lane = threadIdx.x & 63;
  const int ln15 = lane & 15, quad = lane >> 4;
  const int npx0 = wv * 64;                        // wave covers 64 pixels of the row

  int set = 0;
  if constexpr (MODE == 1) set = 1 + sel[b];
  const _Float16* wset = wp + (size_t)set * (7 * 4 * 64 * 32);
  const _Float16* xb   = xp + (size_t)b * (512 * 512 * 16);

  f32x4 acc[4][4];
#pragma unroll
  for (int f = 0; f < 4; ++f)
#pragma unroll
    for (int g = 0; g < 4; ++g) acc[f][g] = (f32x4){0.f, 0.f, 0.f, 0.f};

#pragma unroll 1
  for (int ky = 0; ky < 7; ++ky) {
    const int iy = 2 * oy + ky - 3;
    if ((unsigned)iy >= 512u) continue;            // wave-uniform skip
    const _Float16* xrow = xb + (size_t)iy * (512 * 16);
#pragma unroll
    for (int pair = 0; pair < 4; ++pair) {
      const _Float16* wt = wset + (size_t)((ky * 4 + pair) * 64) * 32;
      f16x8 af[4];
#pragma unroll
      for (int f = 0; f < 4; ++f)
        af[f] = *(const f16x8*)&wt[(f * 16 + ln15) * 32 + quad * 8];
      f16x8 bf[4];
#pragma unroll
      for (int g = 0; g < 4; ++g) {
        const int ox = npx0 + g * 16 + ln15;
        const int ix = 2 * ox + 2 * pair + (quad >> 1) - 3;
        f16x8 v = {};
        if ((unsigned)ix < 512u)
          v = *(const f16x8*)&xrow[ix * 16 + (quad & 1) * 8];
        bf[g] = v;
      }
#pragma unroll
      for (int f = 0; f < 4; ++f)
#pragma unroll
        for (int g = 0; g < 4; ++g)
          acc[f][g] = __builtin_amdgcn_mfma_f32_16x16x32_f16(af[f], bf[g], acc[f][g], 0, 0, 0);
    }
  }

  // epilogue -> fp16 ch-last [b][256][256][64]
#pragma unroll
  for (int f = 0; f < 4; ++f) {
    float scl[4], add[4];
#pragma unroll
    for (int r = 0; r < 4; ++r) {
      const int cout = f * 16 + quad * 4 + r;
      if constexpr (MODE == 0) {
        const float sc = bn_g[cout] * rsqrtf(bn_v[cout] + 1e-5f);
        scl[r] = sc; add[r] = bn_b[cout] - bn_m[cout] * sc;
      } else { scl[r] = 1.f; add[r] = 0.f; }
    }
#pragma unroll
    for (int g = 0; g < 4; ++g) {
      const int pix = npx0 + g * 16 + ln15;
      f16x4 h;
#pragma unroll
      for (int r = 0; r < 4; ++r)
        h[r] = (_Float16)fmaxf(acc[f][g][r] * scl[r] + add[r], 0.f);
      *(f16x4*)&out[((size_t)(b * 256 + oy) * 256 + pix) * 64 + f * 16 + quad * 4] = h;
    }
  }
}

// ---------------- conv3x3 (CINC ch-last fp16 in, 128 ch-last fp16 out) ----------------
// MODE 1: relu. MODE 2: +bias relu.
template<int CINC, int S, int INSZ, int OUTSZ, int MODE>
__global__ __launch_bounds__(256) void conv3m_k(
    const _Float16* __restrict__ xp, const _Float16* __restrict__ wp,
    const float* __restrict__ p_bias, const int* __restrict__ sel,
    _Float16* __restrict__ out)
{
  constexpr int CH = CINC / 32;
  const int oy = blockIdx.x % OUTSZ, b = blockIdx.x / OUTSZ;
  const int wv = threadIdx.x >> 6, lane = threadIdx.x & 63;
  const int ln15 = lane & 15, quad = lane >> 4;
  const int mwb = (wv >> 1) * 64, nwb = (wv & 1) * 64;

  const int e = sel[b];
  const _Float16* we = wp + (size_t)e * (9 * CH * 128 * 32);
  const _Float16* xb = xp + (size_t)b * ((size_t)INSZ * INSZ * CINC);

  f32x4 acc[4][4];
#pragma unroll
  for (int f = 0; f < 4; ++f)
#pragma unroll
    for (int g = 0; g < 4; ++g) acc[f][g] = (f32x4){0.f, 0.f, 0.f, 0.f};

#pragma unroll 1
  for (int ky = 0; ky < 3; ++ky) {
    const int iy = S * oy + ky - 1;
    if ((unsigned)iy >= (unsigned)INSZ) continue;  // wave-uniform skip
    const _Float16* xrow = xb + (size_t)iy * INSZ * CINC;
#pragma unroll
    for (int kx = 0; kx < 3; ++kx) {
#pragma unroll
      for (int ch = 0; ch < CH; ++ch) {
        const _Float16* wt = we + (size_t)(((ky * 3 + kx) * CH + ch) * 128) * 32;
        f16x8 af[4];
#pragma unroll
        for (int f = 0; f < 4; ++f)
          af[f] = *(const f16x8*)&wt[(mwb + f * 16 + ln15) * 32 + quad * 8];
        f16x8 bf[4];
#pragma unroll
        for (int g = 0; g < 4; ++g) {
          const int ox = nwb + g * 16 + ln15;
          const int ix = S * ox + kx - 1;
          f16x8 v = {};
          if ((unsigned)ix < (unsigned)INSZ)
            v = *(const f16x8*)&xrow[(size_t)ix * CINC + ch * 32 + quad * 8];
          bf[g] = v;
        }
#pragma unroll
        for (int f = 0; f < 4; ++f)
#pragma unroll
          for (int g = 0; g < 4; ++g)
            acc[f][g] = __builtin_amdgcn_mfma_f32_16x16x32_f16(af[f], bf[g], acc[f][g], 0, 0, 0);
      }
    }
  }

  // epilogue -> fp16 ch-last [b][OUTSZ][OUTSZ][128]
#pragma unroll
  for (int f = 0; f < 4; ++f) {
#pragma unroll
    for (int g = 0; g < 4; ++g) {
      const int pix = nwb + g * 16 + ln15;
      f16x4 h;
#pragma unroll
      for (int r = 0; r < 4; ++r) {
        const int cout = mwb + f * 16 + quad * 4 + r;
        float v = acc[f][g][r];
        if constexpr (MODE == 2) v += p_bias[e * 128 + cout];
        h[r] = (_Float16)fmaxf(v, 0.f);
      }
      *(f16x4*)&out[((size_t)(b * OUTSZ + oy) * OUTSZ + pix) * 128 + mwb + f * 16 + quad * 4] = h;
    }
  }
}

// ---------------- zero pooled accumulator ----------------
__global__ void zero_k(float* __restrict__ pooled) {
  if (threadIdx.x < 512) pooled[threadIdx.x] = 0.f;
}

// ---------------- maxpool 3x3 s2 p1 on ch-last fp16 feat + partial mean ----------------
__global__ __launch_bounds__(256) void pool_k(
    const _Float16* __restrict__ f, float* __restrict__ pooled)
{
  const int b = blockIdx.x >> 4, grp = blockIdx.x & 15;  // grid 128
  const int c = threadIdx.x & 63, sub = threadIdx.x >> 6;
  const _Float16* fb = f + (size_t)b * 256 * 256 * 64;
  float sum = 0.f;
#pragma unroll
  for (int rr = 0; rr < 2; ++rr) {
    const int py = grp * 8 + sub * 2 + rr;
    for (int px = 0; px < 128; ++px) {
      float m = -1e30f;
#pragma unroll
      for (int dy = 0; dy < 3; ++dy) {
        const int y = 2 * py - 1 + dy;
        if ((unsigned)y < 256u) {
#pragma unroll
          for (int dx = 0; dx < 3; ++dx) {
            const int x = 2 * px - 1 + dx;
            if ((unsigned)x < 256u)
              m = fmaxf(m, (float)fb[((size_t)y * 256 + x) * 64 + c]);
          }
        }
      }
      sum += m;
    }
  }
  __shared__ float red[256];
  red[threadIdx.x] = sum;
  __syncthreads();
  if (threadIdx.x < 64) {
    const float s = red[c] + red[64 + c] + red[128 + c] + red[192 + c];
    atomicAdd(&pooled[b * 64 + c], s);
  }
}

// ---------------- FC + top-1 + aux loss (pooled holds SUMS; /16384) ----------------
__global__ __launch_bounds__(64) void gate_k(
    const float* __restrict__ pooled, const float* __restrict__ fcw,
    const float* __restrict__ fcb, int* __restrict__ sel, float* __restrict__ out_aux)
{
  __shared__ float probs[8][3];
  __shared__ int sidx[8];
  const int b = threadIdx.x;
  if (b < 8) {
    float l[3];
#pragma unroll
    for (int e = 0; e < 3; ++e) {
      float s = fcb[e];
      for (int c = 0; c < 64; ++c)
        s = fmaf(pooled[b * 64 + c] * (1.f / 16384.f), fcw[e * 64 + c], s);
      l[e] = s;
    }
    int best = 0;
    if (l[1] > l[best]) best = 1;
    if (l[2] > l[best]) best = 2;
    sel[b] = best;
    sidx[b] = best;
    const float m = fmaxf(l[0], fmaxf(l[1], l[2]));
    const float e0 = expf(l[0] - m), e1 = expf(l[1] - m), e2 = expf(l[2] - m);
    const float inv = 1.f / (e0 + e1 + e2);
    probs[b][0] = e0 * inv; probs[b][1] = e1 * inv; probs[b][2] = e2 * inv;
  }
  __syncthreads();
  if (threadIdx.x == 0) {
    float cnt[3] = {0.f, 0.f, 0.f}, pr[3] = {0.f, 0.f, 0.f};
    for (int bb = 0; bb < 8; ++bb) {
      cnt[sidx[bb]] += 1.f;
#pragma unroll
      for (int e = 0; e < 3; ++e) pr[e] += probs[bb][e];
    }
    float aux = 0.f;
#pragma unroll
    for (int e = 0; e < 3; ++e) aux += (cnt[e] * 0.125f) * (pr[e] * 0.125f);
    *out_aux = 0.01f * (3.f * aux);
  }
}

// ---------------- head 1x1 conv 128->5 + bias (ch-last fp16 in), scatter ----------------
__global__ __launch_bounds__(256) void head2m_k(
    const _Float16* __restrict__ in, const float* __restrict__ w,
    const float* __restrict__ b2, const int* __restrict__ sel,
    float* __restrict__ out)
{
  const int b = blockIdx.x >> 6;
  const int p = ((blockIdx.x & 63) << 8) + threadIdx.x;  // 0..16383
  const int e = sel[b];
  const float* wp = w + (size_t)e * 5 * 128;
  const _Float16* ip = in + ((size_t)(b << 14) + p) * 128;
  float a0 = 0.f, a1 = 0.f, a2 = 0.f, a3 = 0.f, a4 = 0.f;
#pragma unroll
  for (int cc = 0; cc < 16; ++cc) {
    const f16x8 v8 = *(const f16x8*)&ip[cc * 8];
#pragma unroll
    for (int j = 0; j < 8; ++j) {
      const float v = (float)v8[j];
      const int c = cc * 8 + j;
      a0 = fmaf(v, wp[c], a0);
      a1 = fmaf(v, wp[128 + c], a1);
      a2 = fmaf(v, wp[256 + c], a2);
      a3 = fmaf(v, wp[384 + c], a3);
      a4 = fmaf(v, wp[512 + c], a4);
    }
  }
  a0 += b2[e * 5 + 0]; a1 += b2[e * 5 + 1]; a2 += b2[e * 5 + 2];
  a3 += b2[e * 5 + 3]; a4 += b2[e * 5 + 4];
  out[(b << 14) + p] = a0;                         // hm
  out[131072 + ((b * 2 + 0) << 14) + p] = a1;      // wh c0
  out[131072 + ((b * 2 + 1) << 14) + p] = a2;      // wh c1
  out[393216 + ((b * 2 + 0) << 14) + p] = a3;      // reg c0
  out[393216 + ((b * 2 + 1) << 14) + p] = a4;      // reg c1
}

extern "C" void kernel_launch(void* const* d_in, const int* in_sizes, int n_in,
                              void* d_out, int out_size, void* d_ws, size_t ws_size,
                              hipStream_t stream) {
  const float* x          = (const float*)d_in[0];
  const float* g_conv_w   = (const float*)d_in[1];
  const float* g_bn_gamma = (const float*)d_in[2];
  const float* g_bn_beta  = (const float*)d_in[3];
  const float* g_bn_mean  = (const float*)d_in[4];
  const float* g_bn_var   = (const float*)d_in[5];
  const float* g_fc_w     = (const float*)d_in[6];
  const float* g_fc_b     = (const float*)d_in[7];
  const float* e_conv1_w  = (const float*)d_in[8];
  const float* e_conv2_w  = (const float*)d_in[9];
  const float* e_head_w1  = (const float*)d_in[10];
  const float* e_head_b1  = (const float*)d_in[11];
  const float* e_head_w2  = (const float*)d_in[12];
  const float* e_head_b2  = (const float*)d_in[13];
  float* out = (float*)d_out;

  // ---- workspace layout (f16 units), total ~170 MB ----
  _Float16* xp      = (_Float16*)d_ws;            // 8*512*512*16 = 33,554,432
  _Float16* featbuf = xp + 33554432;               // 8*256*256*64 = 33,554,432 (gating feat, then conv1 out)
  _Float16* y2      = featbuf + 33554432;          // 8*128*128*128 = 16,777,216
  _Float16* w7p     = y2 + 16777216;               // 4*7*4*64*32 = 229,376
  _Float16* w2p     = w7p + 229376;                // 3*9*2*128*32 = 221,184
  _Float16* w3p     = w2p + 221184;                // 3*9*4*128*32 = 442,368
  _Float16* y3      = xp;                          // head1 out aliases xp (dead by then)
  float*    pooled  = (float*)(w3p + 442368);      // 512 f32
  int*      sel     = (int*)(pooled + 512);        // 8 ints

  // ---- preps ----
  prep_x_k<<<8192, 256, 0, stream>>>(x, xp);
  prep_w7_k<<<896, 256, 0, stream>>>(g_conv_w, e_conv1_w, w7p);
  prep_w3_k<64><<<864, 256, 0, stream>>>(e_conv2_w, w2p);
  prep_w3_k<128><<<1728, 256, 0, stream>>>(e_head_w1, w3p);
  zero_k<<<1, 512, 0, stream>>>(pooled);

  // ---- gating path ----
  conv7m_k<0><<<2048, 256, 0, stream>>>(xp, w7p, g_bn_gamma, g_bn_beta,
                                        g_bn_mean, g_bn_var, nullptr, featbuf);
  pool_k<<<128, 256, 0, stream>>>(featbuf, pooled);
  gate_k<<<1, 64, 0, stream>>>(pooled, g_fc_w, g_fc_b, sel, out + 655360);

  // ---- selected-expert path ----
  conv7m_k<1><<<2048, 256, 0, stream>>>(xp, w7p, nullptr, nullptr, nullptr, nullptr,
                                        sel, featbuf);
  conv3m_k<64, 2, 256, 128, 1><<<1024, 256, 0, stream>>>(featbuf, w2p, nullptr, sel, y2);
  conv3m_k<128, 1, 128, 128, 2><<<1024, 256, 0, stream>>>(y2, w3p, e_head_b1, sel, y3);
  head2m_k<<<512, 256, 0, stream>>>(y3, e_head_w2, e_head_b2, sel, out);
}

// Round 5
// 727.334 us; speedup vs baseline: 9.0976x; 1.3512x over previous
//
#include <hip/hip_runtime.h>
#include <cstdint>
#include <cmath>

// B=8, x reshaped (8,15,512,512) fp32.
// gating: conv7x7 s2 p3 (15->64, 256x256) -> BN -> relu -> maxpool3x3 s2 p1 -> mean -> FC(64->3) -> top-1
// expert (selected, top-1 => gate weight 1.0): conv7x7 s2 p3 (15->64) relu -> conv3x3 s2 p1 (64->128) relu
//         -> conv3x3 s1 p1 (128->128)+b relu -> conv1x1 (128->5)+b
// out: hm | wh | reg | 0.01*aux = 655361 floats
//
// R5: R4 structure; pool_k regridded 128->1024 blocks (was 349us at 5.6% occupancy,
// launch-shape starved; HBM floor ~15us).
// Fragment mappings (validated R3/R4): A[m=lane&15][k=quad*8+j], B[k=quad*8+j][n=lane&15],
// C[row=quad*4+r][col=lane&15].

typedef _Float16 f16x8 __attribute__((ext_vector_type(8)));
typedef _Float16 f16x4 __attribute__((ext_vector_type(4)));
typedef float f32x4 __attribute__((ext_vector_type(4)));

// ---------------- prep: x fp32 [b][15][512][512] -> fp16 [b][512][512][16] ----------------
__global__ __launch_bounds__(256) void prep_x_k(
    const float* __restrict__ x, _Float16* __restrict__ xp)
{
  const int t = blockIdx.x * 256 + threadIdx.x;   // 0 .. 8*262144-1
  const int pix = t & 262143;
  const int b   = t >> 18;
  const float* src = x + (size_t)b * 15 * 262144 + pix;
  f16x8 lo, hi;
#pragma unroll
  for (int c = 0; c < 8; ++c)  lo[c] = (_Float16)src[(size_t)c * 262144];
#pragma unroll
  for (int c = 8; c < 15; ++c) hi[c - 8] = (_Float16)src[(size_t)c * 262144];
  hi[7] = (_Float16)0.f;
  *(f16x8*)&xp[(size_t)t * 16]     = lo;
  *(f16x8*)&xp[(size_t)t * 16 + 8] = hi;
}

// ---------------- prep: conv7 weights -> [set4][ky7][pair4][cout64][32] fp16 ----------------
__global__ __launch_bounds__(256) void prep_w7_k(
    const float* __restrict__ gw, const float* __restrict__ ew,
    _Float16* __restrict__ wp)
{
  const int i = blockIdx.x * 256 + threadIdx.x;   // 0 .. 229375
  const int kk   = i & 31;
  const int cout = (i >> 5) & 63;
  const int pair = (i >> 11) & 3;
  const int v    = i >> 13;
  const int ky = v % 7, set = v / 7;
  const int t = kk >> 4, cin = kk & 15;
  const int kx = 2 * pair + t;
  float val = 0.f;
  if (cin < 15 && kx < 7) {
    if (set == 0) val = gw[((cout * 15 + cin) * 7 + ky) * 7 + kx];
    else          val = ew[((((set - 1) * 64 + cout) * 15 + cin) * 7 + ky) * 7 + kx];
  }
  wp[i] = (_Float16)val;
}

// ---------------- prep: 3x3 weights [3][128][CINC][3][3] -> [e][tap9][ch][cout128][32] ----
template<int CINC>
__global__ __launch_bounds__(256) void prep_w3_k(
    const float* __restrict__ w, _Float16* __restrict__ wp)
{
  constexpr int CH = CINC / 32;
  const int i = blockIdx.x * 256 + threadIdx.x;   // 0 .. 3*9*CH*128*32-1
  const int kk   = i & 31;
  const int cout = (i >> 5) & 127;
  int rest = i >> 12;
  const int ch  = rest % CH;  rest /= CH;
  const int tap = rest % 9;
  const int e   = rest / 9;
  const int cin = ch * 32 + kk;
  wp[i] = (_Float16)w[((size_t)(e * 128 + cout) * CINC + cin) * 9 + tap];
}

// ---------------- conv7x7 s2 p3 (16ch-last in, 64ch-last fp16 out) ----------------
template<int MODE>
__global__ __launch_bounds__(256) void conv7m_k(
    const _Float16* __restrict__ xp, const _Float16* __restrict__ wp,
    const float* __restrict__ bn_g, const float* __restrict__ bn_b,
    const float* __restrict__ bn_m, const float* __restrict__ bn_v,
    const int* __restrict__ sel, _Float16* __restrict__ out)
{
  const int oy = blockIdx.x & 255, b = blockIdx.x >> 8;
  const int wv = threadIdx.x >> 6, lane = threadIdx.x & 63;
  const int ln15 = lane & 15, quad = lane >> 4;
  const int npx0 = wv * 64;

  int set = 0;
  if constexpr (MODE == 1) set = 1 + sel[b];
  const _Float16* wset = wp + (size_t)set * (7 * 4 * 64 * 32);
  const _Float16* xb   = xp + (size_t)b * (512 * 512 * 16);

  f32x4 acc[4][4];
#pragma unroll
  for (int f = 0; f < 4; ++f)
#pragma unroll
    for (int g = 0; g < 4; ++g) acc[f][g] = (f32x4){0.f, 0.f, 0.f, 0.f};

#pragma unroll 1
  for (int ky = 0; ky < 7; ++ky) {
    const int iy = 2 * oy + ky - 3;
    if ((unsigned)iy >= 512u) continue;
    const _Float16* xrow = xb + (size_t)iy * (512 * 16);
#pragma unroll
    for (int pair = 0; pair < 4; ++pair) {
      const _Float16* wt = wset + (size_t)((ky * 4 + pair) * 64) * 32;
      f16x8 af[4];
#pragma unroll
      for (int f = 0; f < 4; ++f)
        af[f] = *(const f16x8*)&wt[(f * 16 + ln15) * 32 + quad * 8];
      f16x8 bf[4];
#pragma unroll
      for (int g = 0; g < 4; ++g) {
        const int ox = npx0 + g * 16 + ln15;
        const int ix = 2 * ox + 2 * pair + (quad >> 1) - 3;
        f16x8 v = {};
        if ((unsigned)ix < 512u)
          v = *(const f16x8*)&xrow[ix * 16 + (quad & 1) * 8];
        bf[g] = v;
      }
#pragma unroll
      for (int f = 0; f < 4; ++f)
#pragma unroll
        for (int g = 0; g < 4; ++g)
          acc[f][g] = __builtin_amdgcn_mfma_f32_16x16x32_f16(af[f], bf[g], acc[f][g], 0, 0, 0);
    }
  }

#pragma unroll
  for (int f = 0; f < 4; ++f) {
    float scl[4], add[4];
#pragma unroll
    for (int r = 0; r < 4; ++r) {
      const int cout = f * 16 + quad * 4 + r;
      if constexpr (MODE == 0) {
        const float sc = bn_g[cout] * rsqrtf(bn_v[cout] + 1e-5f);
        scl[r] = sc; add[r] = bn_b[cout] - bn_m[cout] * sc;
      } else { scl[r] = 1.f; add[r] = 0.f; }
    }
#pragma unroll
    for (int g = 0; g < 4; ++g) {
      const int pix = npx0 + g * 16 + ln15;
      f16x4 h;
#pragma unroll
      for (int r = 0; r < 4; ++r)
        h[r] = (_Float16)fmaxf(acc[f][g][r] * scl[r] + add[r], 0.f);
      *(f16x4*)&out[((size_t)(b * 256 + oy) * 256 + pix) * 64 + f * 16 + quad * 4] = h;
    }
  }
}

// ---------------- conv3x3 (CINC ch-last fp16 in, 128 ch-last fp16 out) ----------------
template<int CINC, int S, int INSZ, int OUTSZ, int MODE>
__global__ __launch_bounds__(256) void conv3m_k(
    const _Float16* __restrict__ xp, const _Float16* __restrict__ wp,
    const float* __restrict__ p_bias, const int* __restrict__ sel,
    _Float16* __restrict__ out)
{
  constexpr int CH = CINC / 32;
  const int oy = blockIdx.x % OUTSZ, b = blockIdx.x / OUTSZ;
  const int wv = threadIdx.x >> 6, lane = threadIdx.x & 63;
  const int ln15 = lane & 15, quad = lane >> 4;
  const int mwb = (wv >> 1) * 64, nwb = (wv & 1) * 64;

  const int e = sel[b];
  const _Float16* we = wp + (size_t)e * (9 * CH * 128 * 32);
  const _Float16* xb = xp + (size_t)b * ((size_t)INSZ * INSZ * CINC);

  f32x4 acc[4][4];
#pragma unroll
  for (int f = 0; f < 4; ++f)
#pragma unroll
    for (int g = 0; g < 4; ++g) acc[f][g] = (f32x4){0.f, 0.f, 0.f, 0.f};

#pragma unroll 1
  for (int ky = 0; ky < 3; ++ky) {
    const int iy = S * oy + ky - 1;
    if ((unsigned)iy >= (unsigned)INSZ) continue;
    const _Float16* xrow = xb + (size_t)iy * INSZ * CINC;
#pragma unroll
    for (int kx = 0; kx < 3; ++kx) {
#pragma unroll
      for (int ch = 0; ch < CH; ++ch) {
        const _Float16* wt = we + (size_t)(((ky * 3 + kx) * CH + ch) * 128) * 32;
        f16x8 af[4];
#pragma unroll
        for (int f = 0; f < 4; ++f)
          af[f] = *(const f16x8*)&wt[(mwb + f * 16 + ln15) * 32 + quad * 8];
        f16x8 bf[4];
#pragma unroll
        for (int g = 0; g < 4; ++g) {
          const int ox = nwb + g * 16 + ln15;
          const int ix = S * ox + kx - 1;
          f16x8 v = {};
          if ((unsigned)ix < (unsigned)INSZ)
            v = *(const f16x8*)&xrow[(size_t)ix * CINC + ch * 32 + quad * 8];
          bf[g] = v;
        }
#pragma unroll
        for (int f = 0; f < 4; ++f)
#pragma unroll
          for (int g = 0; g < 4; ++g)
            acc[f][g] = __builtin_amdgcn_mfma_f32_16x16x32_f16(af[f], bf[g], acc[f][g], 0, 0, 0);
      }
    }
  }

#pragma unroll
  for (int f = 0; f < 4; ++f) {
#pragma unroll
    for (int g = 0; g < 4; ++g) {
      const int pix = nwb + g * 16 + ln15;
      f16x4 h;
#pragma unroll
      for (int r = 0; r < 4; ++r) {
        const int cout = mwb + f * 16 + quad * 4 + r;
        float v = acc[f][g][r];
        if constexpr (MODE == 2) v += p_bias[e * 128 + cout];
        h[r] = (_Float16)fmaxf(v, 0.f);
      }
      *(f16x4*)&out[((size_t)(b * OUTSZ + oy) * OUTSZ + pix) * 128 + mwb + f * 16 + quad * 4] = h;
    }
  }
}

// ---------------- zero pooled accumulator ----------------
__global__ void zero_k(float* __restrict__ pooled) {
  if (threadIdx.x < 512) pooled[threadIdx.x] = 0.f;
}

// ---------------- maxpool 3x3 s2 p1 (ch-last fp16) + partial mean ----------------
// R5: grid 1024 (b x 128 output rows); thread = (channel, 32-px group).
__global__ __launch_bounds__(256) void pool_k(
    const _Float16* __restrict__ f, float* __restrict__ pooled)
{
  const int b  = blockIdx.x >> 7;
  const int py = blockIdx.x & 127;
  const int c  = threadIdx.x & 63;
  const int xg = threadIdx.x >> 6;           // 4 groups of 32 px
  const _Float16* fb = f + (size_t)b * 256 * 256 * 64;

  const int y0 = 2 * py - 1;
  float sum = 0.f;
#pragma unroll 1
  for (int j = 0; j < 32; ++j) {
    const int px = xg * 32 + j;
    const int x0 = 2 * px - 1;
    float m = -1e30f;
#pragma unroll
    for (int dy = 0; dy < 3; ++dy) {
      const int y = y0 + dy;
      if ((unsigned)y < 256u) {
#pragma unroll
        for (int dx = 0; dx < 3; ++dx) {
          const int x = x0 + dx;
          if ((unsigned)x < 256u)
            m = fmaxf(m, (float)fb[((size_t)y * 256 + x) * 64 + c]);
        }
      }
    }
    sum += m;
  }
  __shared__ float red[256];
  red[threadIdx.x] = sum;
  __syncthreads();
  if (threadIdx.x < 64) {
    const float s = red[c] + red[64 + c] + red[128 + c] + red[192 + c];
    atomicAdd(&pooled[b * 64 + c], s);
  }
}

// ---------------- FC + top-1 + aux loss (pooled holds SUMS; /16384) ----------------
__global__ __launch_bounds__(64) void gate_k(
    const float* __restrict__ pooled, const float* __restrict__ fcw,
    const float* __restrict__ fcb, int* __restrict__ sel, float* __restrict__ out_aux)
{
  __shared__ float probs[8][3];
  __shared__ int sidx[8];
  const int b = threadIdx.x;
  if (b < 8) {
    float l[3];
#pragma unroll
    for (int e = 0; e < 3; ++e) {
      float s = fcb[e];
      for (int c = 0; c < 64; ++c)
        s = fmaf(pooled[b * 64 + c] * (1.f / 16384.f), fcw[e * 64 + c], s);
      l[e] = s;
    }
    int best = 0;
    if (l[1] > l[best]) best = 1;
    if (l[2] > l[best]) best = 2;
    sel[b] = best;
    sidx[b] = best;
    const float m = fmaxf(l[0], fmaxf(l[1], l[2]));
    const float e0 = expf(l[0] - m), e1 = expf(l[1] - m), e2 = expf(l[2] - m);
    const float inv = 1.f / (e0 + e1 + e2);
    probs[b][0] = e0 * inv; probs[b][1] = e1 * inv; probs[b][2] = e2 * inv;
  }
  __syncthreads();
  if (threadIdx.x == 0) {
    float cnt[3] = {0.f, 0.f, 0.f}, pr[3] = {0.f, 0.f, 0.f};
    for (int bb = 0; bb < 8; ++bb) {
      cnt[sidx[bb]] += 1.f;
#pragma unroll
      for (int e = 0; e < 3; ++e) pr[e] += probs[bb][e];
    }
    float aux = 0.f;
#pragma unroll
    for (int e = 0; e < 3; ++e) aux += (cnt[e] * 0.125f) * (pr[e] * 0.125f);
    *out_aux = 0.01f * (3.f * aux);
  }
}

// ---------------- head 1x1 conv 128->5 + bias (ch-last fp16 in), scatter ----------------
__global__ __launch_bounds__(256) void head2m_k(
    const _Float16* __restrict__ in, const float* __restrict__ w,
    const float* __restrict__ b2, const int* __restrict__ sel,
    float* __restrict__ out)
{
  const int b = blockIdx.x >> 6;
  const int p = ((blockIdx.x & 63) << 8) + threadIdx.x;  // 0..16383
  const int e = sel[b];
  const float* wp = w + (size_t)e * 5 * 128;
  const _Float16* ip = in + ((size_t)(b << 14) + p) * 128;
  float a0 = 0.f, a1 = 0.f, a2 = 0.f, a3 = 0.f, a4 = 0.f;
#pragma unroll
  for (int cc = 0; cc < 16; ++cc) {
    const f16x8 v8 = *(const f16x8*)&ip[cc * 8];
#pragma unroll
    for (int j = 0; j < 8; ++j) {
      const float v = (float)v8[j];
      const int c = cc * 8 + j;
      a0 = fmaf(v, wp[c], a0);
      a1 = fmaf(v, wp[128 + c], a1);
      a2 = fmaf(v, wp[256 + c], a2);
      a3 = fmaf(v, wp[384 + c], a3);
      a4 = fmaf(v, wp[512 + c], a4);
    }
  }
  a0 += b2[e * 5 + 0]; a1 += b2[e * 5 + 1]; a2 += b2[e * 5 + 2];
  a3 += b2[e * 5 + 3]; a4 += b2[e * 5 + 4];
  out[(b << 14) + p] = a0;                         // hm
  out[131072 + ((b * 2 + 0) << 14) + p] = a1;      // wh c0
  out[131072 + ((b * 2 + 1) << 14) + p] = a2;      // wh c1
  out[393216 + ((b * 2 + 0) << 14) + p] = a3;      // reg c0
  out[393216 + ((b * 2 + 1) << 14) + p] = a4;      // reg c1
}

extern "C" void kernel_launch(void* const* d_in, const int* in_sizes, int n_in,
                              void* d_out, int out_size, void* d_ws, size_t ws_size,
                              hipStream_t stream) {
  const float* x          = (const float*)d_in[0];
  const float* g_conv_w   = (const float*)d_in[1];
  const float* g_bn_gamma = (const float*)d_in[2];
  const float* g_bn_beta  = (const float*)d_in[3];
  const float* g_bn_mean  = (const float*)d_in[4];
  const float* g_bn_var   = (const float*)d_in[5];
  const float* g_fc_w     = (const float*)d_in[6];
  const float* g_fc_b     = (const float*)d_in[7];
  const float* e_conv1_w  = (const float*)d_in[8];
  const float* e_conv2_w  = (const float*)d_in[9];
  const float* e_head_w1  = (const float*)d_in[10];
  const float* e_head_b1  = (const float*)d_in[11];
  const float* e_head_w2  = (const float*)d_in[12];
  const float* e_head_b2  = (const float*)d_in[13];
  float* out = (float*)d_out;

  // ---- workspace layout (f16 units), total ~170 MB ----
  _Float16* xp      = (_Float16*)d_ws;             // 8*512*512*16 = 33,554,432
  _Float16* featbuf = xp + 33554432;               // 8*256*256*64 = 33,554,432
  _Float16* y2      = featbuf + 33554432;          // 8*128*128*128 = 16,777,216
  _Float16* w7p     = y2 + 16777216;               // 229,376
  _Float16* w2p     = w7p + 229376;                // 221,184
  _Float16* w3p     = w2p + 221184;                // 442,368
  _Float16* y3      = xp;                          // head1 out aliases xp (dead by then)
  float*    pooled  = (float*)(w3p + 442368);      // 512 f32
  int*      sel     = (int*)(pooled + 512);        // 8 ints

  // ---- preps ----
  prep_x_k<<<8192, 256, 0, stream>>>(x, xp);
  prep_w7_k<<<896, 256, 0, stream>>>(g_conv_w, e_conv1_w, w7p);
  prep_w3_k<64><<<864, 256, 0, stream>>>(e_conv2_w, w2p);
  prep_w3_k<128><<<1728, 256, 0, stream>>>(e_head_w1, w3p);
  zero_k<<<1, 512, 0, stream>>>(pooled);

  // ---- gating path ----
  conv7m_k<0><<<2048, 256, 0, stream>>>(xp, w7p, g_bn_gamma, g_bn_beta,
                                        g_bn_mean, g_bn_var, nullptr, featbuf);
  pool_k<<<1024, 256, 0, stream>>>(featbuf, pooled);
  gate_k<<<1, 64, 0, stream>>>(pooled, g_fc_w, g_fc_b, sel, out + 655360);

  // ---- selected-expert path ----
  conv7m_k<1><<<2048, 256, 0, stream>>>(xp, w7p, nullptr, nullptr, nullptr, nullptr,
                                        sel, featbuf);
  conv3m_k<64, 2, 256, 128, 1><<<1024, 256, 0, stream>>>(featbuf, w2p, nullptr, sel, y2);
  conv3m_k<128, 1, 128, 128, 2><<<1024, 256, 0, stream>>>(y2, w3p, e_head_b1, sel, y3);
  head2m_k<<<512, 256, 0, stream>>>(y3, e_head_w2, e_head_b2, sel, out);
}

// Round 6
// 722.259 us; speedup vs baseline: 9.1615x; 1.0070x over previous
//
#include <hip/hip_runtime.h>
#include <cstdint>
#include <cmath>

// B=8, x reshaped (8,15,512,512) fp32.
// gating: conv7x7 s2 p3 (15->64, 256x256) -> BN -> relu -> maxpool3x3 s2 p1 -> mean -> FC(64->3) -> top-1
// expert (selected, top-1 => gate weight 1.0): conv7x7 s2 p3 (15->64) relu -> conv3x3 s2 p1 (64->128) relu
//         -> conv3x3 s1 p1 (128->128)+b relu -> conv1x1 (128->5)+b
// out: hm | wh | reg | 0.01*aux = 655361 floats
//
// R6: conv kernels fully straight-line (ky unrolled, row-bound folded into the
// per-lane load predicate -> no per-ky dependency fences), plus LDS-staged
// epilogue for full-line coalesced stores (R5 showed 2x write amplification
// + RMW fetch from 32B-chunk stores).
// Fragment mappings (validated R3/R4): A[m=lane&15][k=quad*8+j],
// B[k=quad*8+j][n=lane&15], C[row=quad*4+r][col=lane&15].

typedef _Float16 f16x8 __attribute__((ext_vector_type(8)));
typedef _Float16 f16x4 __attribute__((ext_vector_type(4)));
typedef float f32x4 __attribute__((ext_vector_type(4)));

// ---------------- prep: x fp32 [b][15][512][512] -> fp16 [b][512][512][16] ----------------
__global__ __launch_bounds__(256) void prep_x_k(
    const float* __restrict__ x, _Float16* __restrict__ xp)
{
  const int t = blockIdx.x * 256 + threadIdx.x;   // 0 .. 8*262144-1
  const int pix = t & 262143;
  const int b   = t >> 18;
  const float* src = x + (size_t)b * 15 * 262144 + pix;
  f16x8 lo, hi;
#pragma unroll
  for (int c = 0; c < 8; ++c)  lo[c] = (_Float16)src[(size_t)c * 262144];
#pragma unroll
  for (int c = 8; c < 15; ++c) hi[c - 8] = (_Float16)src[(size_t)c * 262144];
  hi[7] = (_Float16)0.f;
  *(f16x8*)&xp[(size_t)t * 16]     = lo;
  *(f16x8*)&xp[(size_t)t * 16 + 8] = hi;
}

// ---------------- prep: conv7 weights -> [set4][ky7][pair4][cout64][32] fp16 ----------------
__global__ __launch_bounds__(256) void prep_w7_k(
    const float* __restrict__ gw, const float* __restrict__ ew,
    _Float16* __restrict__ wp)
{
  const int i = blockIdx.x * 256 + threadIdx.x;   // 0 .. 229375
  const int kk   = i & 31;
  const int cout = (i >> 5) & 63;
  const int pair = (i >> 11) & 3;
  const int v    = i >> 13;
  const int ky = v % 7, set = v / 7;
  const int t = kk >> 4, cin = kk & 15;
  const int kx = 2 * pair + t;
  float val = 0.f;
  if (cin < 15 && kx < 7) {
    if (set == 0) val = gw[((cout * 15 + cin) * 7 + ky) * 7 + kx];
    else          val = ew[((((set - 1) * 64 + cout) * 15 + cin) * 7 + ky) * 7 + kx];
  }
  wp[i] = (_Float16)val;
}

// ---------------- prep: 3x3 weights [3][128][CINC][3][3] -> [e][tap9][ch][cout128][32] ----
template<int CINC>
__global__ __launch_bounds__(256) void prep_w3_k(
    const float* __restrict__ w, _Float16* __restrict__ wp)
{
  constexpr int CH = CINC / 32;
  const int i = blockIdx.x * 256 + threadIdx.x;   // 0 .. 3*9*CH*128*32-1
  const int kk   = i & 31;
  const int cout = (i >> 5) & 127;
  int rest = i >> 12;
  const int ch  = rest % CH;  rest /= CH;
  const int tap = rest % 9;
  const int e   = rest / 9;
  const int cin = ch * 32 + kk;
  wp[i] = (_Float16)w[((size_t)(e * 128 + cout) * CINC + cin) * 9 + tap];
}

// ---------------- conv7x7 s2 p3 (16ch-last in, 64ch-last fp16 out) ----------------
template<int MODE>
__global__ __launch_bounds__(256, 3) void conv7m_k(
    const _Float16* __restrict__ xp, const _Float16* __restrict__ wp,
    const float* __restrict__ bn_g, const float* __restrict__ bn_b,
    const float* __restrict__ bn_m, const float* __restrict__ bn_v,
    const int* __restrict__ sel, _Float16* __restrict__ out)
{
  __shared__ _Float16 st[4][64 * 72];              // per-wave epilogue stage, 72-f16 rows
  const int oy = blockIdx.x & 255, b = blockIdx.x >> 8;
  const int wv = threadIdx.x >> 6, lane = threadIdx.x & 63;
  const int ln15 = lane & 15, quad = lane >> 4;
  const int npx0 = wv * 64;

  int set = 0;
  if constexpr (MODE == 1) set = 1 + sel[b];
  const _Float16* wset = wp + (size_t)set * (7 * 4 * 64 * 32);
  const _Float16* xb   = xp + (size_t)b * (512 * 512 * 16);

  f32x4 acc[4][4];
#pragma unroll
  for (int f = 0; f < 4; ++f)
#pragma unroll
    for (int g = 0; g < 4; ++g) acc[f][g] = (f32x4){0.f, 0.f, 0.f, 0.f};

  const int iyb = 2 * oy - 3;
#pragma unroll
  for (int ky = 0; ky < 7; ++ky) {
    const int iy = iyb + ky;
    const bool rok = (unsigned)iy < 512u;          // folded into per-lane pred (no branch)
    const _Float16* xrow = xb + (size_t)iy * (512 * 16);
#pragma unroll
    for (int pair = 0; pair < 4; ++pair) {
      const _Float16* wt = wset + (size_t)((ky * 4 + pair) * 64) * 32;
      f16x8 af[4];
#pragma unroll
      for (int f = 0; f < 4; ++f)
        af[f] = *(const f16x8*)&wt[(f * 16 + ln15) * 32 + quad * 8];
      f16x8 bf[4];
#pragma unroll
      for (int g = 0; g < 4; ++g) {
        const int ox = npx0 + g * 16 + ln15;
        const int ix = 2 * ox + 2 * pair + (quad >> 1) - 3;
        f16x8 v = {};
        if (rok && (unsigned)ix < 512u)
          v = *(const f16x8*)&xrow[ix * 16 + (quad & 1) * 8];
        bf[g] = v;
      }
#pragma unroll
      for (int f = 0; f < 4; ++f)
#pragma unroll
        for (int g = 0; g < 4; ++g)
          acc[f][g] = __builtin_amdgcn_mfma_f32_16x16x32_f16(af[f], bf[g], acc[f][g], 0, 0, 0);
    }
  }

  // ---- epilogue: BN/relu -> LDS stage -> full-line stores ----
  _Float16* sw = &st[wv][0];
#pragma unroll
  for (int f = 0; f < 4; ++f) {
    float scl[4], add[4];
#pragma unroll
    for (int r = 0; r < 4; ++r) {
      const int cout = f * 16 + quad * 4 + r;
      if constexpr (MODE == 0) {
        const float sc = bn_g[cout] * rsqrtf(bn_v[cout] + 1e-5f);
        scl[r] = sc; add[r] = bn_b[cout] - bn_m[cout] * sc;
      } else { scl[r] = 1.f; add[r] = 0.f; }
    }
#pragma unroll
    for (int g = 0; g < 4; ++g) {
      f16x4 h;
#pragma unroll
      for (int r = 0; r < 4; ++r)
        h[r] = (_Float16)fmaxf(acc[f][g][r] * scl[r] + add[r], 0.f);
      *(f16x4*)&sw[(g * 16 + ln15) * 72 + f * 16 + quad * 4] = h;
    }
  }
  __syncthreads();
  const size_t rowbase = ((size_t)(b * 256 + oy) * 256 + npx0) * 64;
#pragma unroll
  for (int i = 0; i < 8; ++i) {
    const int pxl = (lane >> 3) + i * 8;
    const int c8  = (lane & 7) * 8;
    const f16x8 v = *(const f16x8*)&sw[pxl * 72 + c8];
    *(f16x8*)&out[rowbase + (size_t)pxl * 64 + c8] = v;
  }
}

// ---------------- conv3x3 (CINC ch-last fp16 in, 128 ch-last fp16 out) ----------------
template<int CINC, int S, int INSZ, int OUTSZ, int MODE>
__global__ __launch_bounds__(256, 3) void conv3m_k(
    const _Float16* __restrict__ xp, const _Float16* __restrict__ wp,
    const float* __restrict__ p_bias, const int* __restrict__ sel,
    _Float16* __restrict__ out)
{
  constexpr int CH = CINC / 32;
  __shared__ _Float16 st[4][64 * 72];
  const int oy = blockIdx.x % OUTSZ, b = blockIdx.x / OUTSZ;
  const int wv = threadIdx.x >> 6, lane = threadIdx.x & 63;
  const int ln15 = lane & 15, quad = lane >> 4;
  const int mwb = (wv >> 1) * 64, nwb = (wv & 1) * 64;

  const int e = sel[b];
  const _Float16* we = wp + (size_t)e * (9 * CH * 128 * 32);
  const _Float16* xb = xp + (size_t)b * ((size_t)INSZ * INSZ * CINC);

  f32x4 acc[4][4];
#pragma unroll
  for (int f = 0; f < 4; ++f)
#pragma unroll
    for (int g = 0; g < 4; ++g) acc[f][g] = (f32x4){0.f, 0.f, 0.f, 0.f};

#pragma unroll
  for (int ky = 0; ky < 3; ++ky) {
    const int iy = S * oy + ky - 1;
    const bool rok = (unsigned)iy < (unsigned)INSZ;
    const _Float16* xrow = xb + (size_t)iy * INSZ * CINC;
#pragma unroll
    for (int kx = 0; kx < 3; ++kx) {
#pragma unroll
      for (int ch = 0; ch < CH; ++ch) {
        const _Float16* wt = we + (size_t)(((ky * 3 + kx) * CH + ch) * 128) * 32;
        f16x8 af[4];
#pragma unroll
        for (int f = 0; f < 4; ++f)
          af[f] = *(const f16x8*)&wt[(mwb + f * 16 + ln15) * 32 + quad * 8];
        f16x8 bf[4];
#pragma unroll
        for (int g = 0; g < 4; ++g) {
          const int ox = nwb + g * 16 + ln15;
          const int ix = S * ox + kx - 1;
          f16x8 v = {};
          if (rok && (unsigned)ix < (unsigned)INSZ)
            v = *(const f16x8*)&xrow[(size_t)ix * CINC + ch * 32 + quad * 8];
          bf[g] = v;
        }
#pragma unroll
        for (int f = 0; f < 4; ++f)
#pragma unroll
          for (int g = 0; g < 4; ++g)
            acc[f][g] = __builtin_amdgcn_mfma_f32_16x16x32_f16(af[f], bf[g], acc[f][g], 0, 0, 0);
      }
    }
  }

  // ---- epilogue: bias/relu -> LDS stage -> 128B half-line stores ----
  _Float16* sw = &st[wv][0];
#pragma unroll
  for (int f = 0; f < 4; ++f) {
#pragma unroll
    for (int g = 0; g < 4; ++g) {
      f16x4 h;
#pragma unroll
      for (int r = 0; r < 4; ++r) {
        const int cout = mwb + f * 16 + quad * 4 + r;
        float v = acc[f][g][r];
        if constexpr (MODE == 2) v += p_bias[e * 128 + cout];
        h[r] = (_Float16)fmaxf(v, 0.f);
      }
      *(f16x4*)&sw[(g * 16 + ln15) * 72 + f * 16 + quad * 4] = h;
    }
  }
  __syncthreads();
  const size_t rowbase = ((size_t)(b * OUTSZ + oy) * OUTSZ + nwb) * 128 + mwb;
#pragma unroll
  for (int i = 0; i < 8; ++i) {
    const int pxl = (lane >> 3) + i * 8;
    const int c8  = (lane & 7) * 8;
    const f16x8 v = *(const f16x8*)&sw[pxl * 72 + c8];
    *(f16x8*)&out[rowbase + (size_t)pxl * 128 + c8] = v;
  }
}

// ---------------- zero pooled accumulator ----------------
__global__ void zero_k(float* __restrict__ pooled) {
  if (threadIdx.x < 512) pooled[threadIdx.x] = 0.f;
}

// ---------------- maxpool 3x3 s2 p1 (ch-last fp16) + partial mean ----------------
__global__ __launch_bounds__(256) void pool_k(
    const _Float16* __restrict__ f, float* __restrict__ pooled)
{
  const int b  = blockIdx.x >> 7;
  const int py = blockIdx.x & 127;
  const int c  = threadIdx.x & 63;
  const int xg = threadIdx.x >> 6;           // 4 groups of 32 px
  const _Float16* fb = f + (size_t)b * 256 * 256 * 64;

  const int y0 = 2 * py - 1;
  float sum = 0.f;
#pragma unroll 1
  for (int j = 0; j < 32; ++j) {
    const int px = xg * 32 + j;
    const int x0 = 2 * px - 1;
    float m = -1e30f;
#pragma unroll
    for (int dy = 0; dy < 3; ++dy) {
      const int y = y0 + dy;
      if ((unsigned)y < 256u) {
#pragma unroll
        for (int dx = 0; dx < 3; ++dx) {
          const int x = x0 + dx;
          if ((unsigned)x < 256u)
            m = fmaxf(m, (float)fb[((size_t)y * 256 + x) * 64 + c]);
        }
      }
    }
    sum += m;
  }
  __shared__ float red[256];
  red[threadIdx.x] = sum;
  __syncthreads();
  if (threadIdx.x < 64) {
    const float s = red[c] + red[64 + c] + red[128 + c] + red[192 + c];
    atomicAdd(&pooled[b * 64 + c], s);
  }
}

// ---------------- FC + top-1 + aux loss (pooled holds SUMS; /16384) ----------------
__global__ __launch_bounds__(64) void gate_k(
    const float* __restrict__ pooled, const float* __restrict__ fcw,
    const float* __restrict__ fcb, int* __restrict__ sel, float* __restrict__ out_aux)
{
  __shared__ float probs[8][3];
  __shared__ int sidx[8];
  const int b = threadIdx.x;
  if (b < 8) {
    float l[3];
#pragma unroll
    for (int e = 0; e < 3; ++e) {
      float s = fcb[e];
      for (int c = 0; c < 64; ++c)
        s = fmaf(pooled[b * 64 + c] * (1.f / 16384.f), fcw[e * 64 + c], s);
      l[e] = s;
    }
    int best = 0;
    if (l[1] > l[best]) best = 1;
    if (l[2] > l[best]) best = 2;
    sel[b] = best;
    sidx[b] = best;
    const float m = fmaxf(l[0], fmaxf(l[1], l[2]));
    const float e0 = expf(l[0] - m), e1 = expf(l[1] - m), e2 = expf(l[2] - m);
    const float inv = 1.f / (e0 + e1 + e2);
    probs[b][0] = e0 * inv; probs[b][1] = e1 * inv; probs[b][2] = e2 * inv;
  }
  __syncthreads();
  if (threadIdx.x == 0) {
    float cnt[3] = {0.f, 0.f, 0.f}, pr[3] = {0.f, 0.f, 0.f};
    for (int bb = 0; bb < 8; ++bb) {
      cnt[sidx[bb]] += 1.f;
#pragma unroll
      for (int e = 0; e < 3; ++e) pr[e] += probs[bb][e];
    }
    float aux = 0.f;
#pragma unroll
    for (int e = 0; e < 3; ++e) aux += (cnt[e] * 0.125f) * (pr[e] * 0.125f);
    *out_aux = 0.01f * (3.f * aux);
  }
}

// ---------------- head 1x1 conv 128->5 + bias (ch-last fp16 in), scatter ----------------
__global__ __launch_bounds__(256) void head2m_k(
    const _Float16* __restrict__ in, const float* __restrict__ w,
    const float* __restrict__ b2, const int* __restrict__ sel,
    float* __restrict__ out)
{
  const int b = blockIdx.x >> 6;
  const int p = ((blockIdx.x & 63) << 8) + threadIdx.x;  // 0..16383
  const int e = sel[b];
  const float* wp = w + (size_t)e * 5 * 128;
  const _Float16* ip = in + ((size_t)(b << 14) + p) * 128;
  float a0 = 0.f, a1 = 0.f, a2 = 0.f, a3 = 0.f, a4 = 0.f;
#pragma unroll
  for (int cc = 0; cc < 16; ++cc) {
    const f16x8 v8 = *(const f16x8*)&ip[cc * 8];
#pragma unroll
    for (int j = 0; j < 8; ++j) {
      const float v = (float)v8[j];
      const int c = cc * 8 + j;
      a0 = fmaf(v, wp[c], a0);
      a1 = fmaf(v, wp[128 + c], a1);
      a2 = fmaf(v, wp[256 + c], a2);
      a3 = fmaf(v, wp[384 + c], a3);
      a4 = fmaf(v, wp[512 + c], a4);
    }
  }
  a0 += b2[e * 5 + 0]; a1 += b2[e * 5 + 1]; a2 += b2[e * 5 + 2];
  a3 += b2[e * 5 + 3]; a4 += b2[e * 5 + 4];
  out[(b << 14) + p] = a0;                         // hm
  out[131072 + ((b * 2 + 0) << 14) + p] = a1;      // wh c0
  out[131072 + ((b * 2 + 1) << 14) + p] = a2;      // wh c1
  out[393216 + ((b * 2 + 0) << 14) + p] = a3;      // reg c0
  out[393216 + ((b * 2 + 1) << 14) + p] = a4;      // reg c1
}

extern "C" void kernel_launch(void* const* d_in, const int* in_sizes, int n_in,
                              void* d_out, int out_size, void* d_ws, size_t ws_size,
                              hipStream_t stream) {
  const float* x          = (const float*)d_in[0];
  const float* g_conv_w   = (const float*)d_in[1];
  const float* g_bn_gamma = (const float*)d_in[2];
  const float* g_bn_beta  = (const float*)d_in[3];
  const float* g_bn_mean  = (const float*)d_in[4];
  const float* g_bn_var   = (const float*)d_in[5];
  const float* g_fc_w     = (const float*)d_in[6];
  const float* g_fc_b     = (const float*)d_in[7];
  const float* e_conv1_w  = (const float*)d_in[8];
  const float* e_conv2_w  = (const float*)d_in[9];
  const float* e_head_w1  = (const float*)d_in[10];
  const float* e_head_b1  = (const float*)d_in[11];
  const float* e_head_w2  = (const float*)d_in[12];
  const float* e_head_b2  = (const float*)d_in[13];
  float* out = (float*)d_out;

  // ---- workspace layout (f16 units), total ~170 MB ----
  _Float16* xp      = (_Float16*)d_ws;             // 8*512*512*16 = 33,554,432
  _Float16* featbuf = xp + 33554432;               // 8*256*256*64 = 33,554,432
  _Float16* y2      = featbuf + 33554432;          // 8*128*128*128 = 16,777,216
  _Float16* w7p     = y2 + 16777216;               // 229,376
  _Float16* w2p     = w7p + 229376;                // 221,184
  _Float16* w3p     = w2p + 221184;                // 442,368
  _Float16* y3      = xp;                          // head1 out aliases xp (dead by then)
  float*    pooled  = (float*)(w3p + 442368);      // 512 f32
  int*      sel     = (int*)(pooled + 512);        // 8 ints

  // ---- preps ----
  prep_x_k<<<8192, 256, 0, stream>>>(x, xp);
  prep_w7_k<<<896, 256, 0, stream>>>(g_conv_w, e_conv1_w, w7p);
  prep_w3_k<64><<<864, 256, 0, stream>>>(e_conv2_w, w2p);
  prep_w3_k<128><<<1728, 256, 0, stream>>>(e_head_w1, w3p);
  zero_k<<<1, 512, 0, stream>>>(pooled);

  // ---- gating path ----
  conv7m_k<0><<<2048, 256, 0, stream>>>(xp, w7p, g_bn_gamma, g_bn_beta,
                                        g_bn_mean, g_bn_var, nullptr, featbuf);
  pool_k<<<1024, 256, 0, stream>>>(featbuf, pooled);
  gate_k<<<1, 64, 0, stream>>>(pooled, g_fc_w, g_fc_b, sel, out + 655360);

  // ---- selected-expert path ----
  conv7m_k<1><<<2048, 256, 0, stream>>>(xp, w7p, nullptr, nullptr, nullptr, nullptr,
                                        sel, featbuf);
  conv3m_k<64, 2, 256, 128, 1><<<1024, 256, 0, stream>>>(featbuf, w2p, nullptr, sel, y2);
  conv3m_k<128, 1, 128, 128, 2><<<1024, 256, 0, stream>>>(y2, w3p, e_head_b1, sel, y3);
  head2m_k<<<512, 256, 0, stream>>>(y3, e_head_w2, e_head_b2, sel, out);
}